// Round 1
// baseline (742.725 us; speedup 1.0000x reference)
//
#include <hip/hip_runtime.h>
#include <math.h>

// GATv2 2-layer: N=50000, E=800000, HEADS=8, C=32, ODIM=256, IN_C=64
#define HEADS 8
#define CDIM 32
#define ODIM 256

__device__ __forceinline__ float lrelu(float v, float s){ return v > 0.f ? v : s*v; }

// ---------------- CSR build ----------------
__global__ void zero_counts_kernel(int* __restrict__ counts, int n){
  int i = blockIdx.x*256 + threadIdx.x;
  if (i < n) counts[i] = 0;
}

__global__ void count_kernel(const int* __restrict__ src, const int* __restrict__ dst,
                             int* __restrict__ counts, int e){
  int i = blockIdx.x*256 + threadIdx.x;
  if (i < e){
    int s = src[i], d = dst[i];
    if (s != d) atomicAdd(counts + d, 1);   // src==dst originals are masked (PyG removes them)
  }
}

__global__ __launch_bounds__(1024) void scan_kernel(const int* __restrict__ counts,
    int* __restrict__ indptr, int* __restrict__ cursor, int n){
  __shared__ int sums[1024];
  __shared__ int s_carry;
  int t = threadIdx.x;
  if (t == 0) s_carry = 0;
  __syncthreads();
  for (int base = 0; base < n; base += 8192){
    int idx0 = base + t*8;
    int v[8]; int local = 0;
#pragma unroll
    for (int j=0;j<8;j++){
      int i = idx0 + j;
      int c = (i < n) ? counts[i] : 0;
      v[j] = c; local += c;
    }
    sums[t] = local;
    __syncthreads();
    for (int off=1; off<1024; off<<=1){
      int tmp = (t >= off) ? sums[t-off] : 0;
      __syncthreads();
      sums[t] += tmp;
      __syncthreads();
    }
    int excl = sums[t] - local + s_carry;
#pragma unroll
    for (int j=0;j<8;j++){
      int i = idx0 + j;
      if (i < n){ indptr[i] = excl; cursor[i] = excl; }
      excl += v[j];
    }
    __syncthreads();
    if (t == 1023) s_carry += sums[1023];
    __syncthreads();
  }
  if (t == 0) indptr[n] = s_carry;
}

__global__ void scatter_kernel(const int* __restrict__ src, const int* __restrict__ dst,
                               int* __restrict__ cursor, int* __restrict__ csr_src, int e){
  int i = blockIdx.x*256 + threadIdx.x;
  if (i < e){
    int s = src[i], d = dst[i];
    if (s != d){
      int p = atomicAdd(cursor + d, 1);
      csr_src[p] = s;
    }
  }
}

// ---------------- dense GEMM: out[n,o] = sum_k X[n,k]*W[o,k] + b[o] ----------------
// blockIdx.y selects (Wl,bl,outl) vs (Wr,br,outr). W^T staged in LDS [K][256]
// (2-way bank aliasing only, free). x rows are wave-uniform -> scalar loads.
template<int K>
__global__ __launch_bounds__(256) void gemm_kernel(const float* __restrict__ X,
    const float* __restrict__ Wl, const float* __restrict__ bl,
    const float* __restrict__ Wr, const float* __restrict__ br,
    float* __restrict__ outl, float* __restrict__ outr, int n){
  __shared__ float wlds[K*ODIM];
  const float* W = blockIdx.y ? Wr : Wl;
  const float* b = blockIdx.y ? br : bl;
  float* out = blockIdx.y ? outr : outl;
  int t = threadIdx.x;
  for (int k = 0; k < K; ++k)
    wlds[k*ODIM + t] = W[t*K + k];     // thread t owns output channel t
  float bias = b[t];
  __syncthreads();
  for (int n0 = blockIdx.x*4; n0 < n; n0 += gridDim.x*4){
    int rem = n - n0;
    const float* x0 = X + (size_t)n0*K;
    const float* x1 = X + (size_t)(n0 + (rem>1 ? 1 : 0))*K;
    const float* x2 = X + (size_t)(n0 + (rem>2 ? 2 : 0))*K;
    const float* x3 = X + (size_t)(n0 + (rem>3 ? 3 : 0))*K;
    float a0=bias, a1=bias, a2=bias, a3=bias;
#pragma unroll
    for (int k=0;k<K;k++){
      float w = wlds[k*ODIM + t];
      a0 = fmaf(x0[k], w, a0);
      a1 = fmaf(x1[k], w, a1);
      a2 = fmaf(x2[k], w, a2);
      a3 = fmaf(x3[k], w, a3);
    }
    float* o = out + (size_t)n0*ODIM + t;
    o[0] = a0;
    if (rem>1) o[ODIM]   = a1;
    if (rem>2) o[2*ODIM] = a2;
    if (rem>3) o[3*ODIM] = a3;
  }
}

// ---------------- fused edge softmax + aggregate, one wave per node ----------------
// lane l: head h = l>>3, channels 4*(l&7)..+3  => flat offset 4*l (coalesced float4).
// Online softmax over incoming edges (self-loop seeds the state).
__global__ __launch_bounds__(256) void edge_kernel(
    const float* __restrict__ xl, const float* __restrict__ xr,
    const float* __restrict__ att, const float* __restrict__ bias,
    const int* __restrict__ indptr, const int* __restrict__ csr_src,
    float* __restrict__ out, int n, int act)
{
  int wid = blockIdx.x*4 + (threadIdx.x >> 6);
  if (wid >= n) return;
  int lane = threadIdx.x & 63;
  float4 attv = *(const float4*)(att + 4*lane);
  float4 xr4  = *(const float4*)(xr + (size_t)wid*ODIM + 4*lane);
  float4 xv   = *(const float4*)(xl + (size_t)wid*ODIM + 4*lane);

  // self-loop seeds online-softmax state
  float mx = lrelu(xv.x + xr4.x, 0.2f);
  float my = lrelu(xv.y + xr4.y, 0.2f);
  float mz = lrelu(xv.z + xr4.z, 0.2f);
  float mw = lrelu(xv.w + xr4.w, 0.2f);
  float p = mx*attv.x + my*attv.y + mz*attv.z + mw*attv.w;
  p += __shfl_xor(p, 1);
  p += __shfl_xor(p, 2);
  p += __shfl_xor(p, 4);
  float mrun = p;
  float denom = 1.f;
  float4 acc = xv;

  int beg = __builtin_amdgcn_readfirstlane(indptr[wid]);
  int end = __builtin_amdgcn_readfirstlane(indptr[wid+1]);
  int ecur = beg;
  float4 nxt = make_float4(0.f,0.f,0.f,0.f);
  if (ecur < end){
    int s0 = __builtin_amdgcn_readfirstlane(csr_src[ecur]);
    nxt = *(const float4*)(xl + (size_t)s0*ODIM + 4*lane);
  }
  while (ecur < end){
    float4 cur = nxt;
    ++ecur;
    if (ecur < end){
      int s1 = __builtin_amdgcn_readfirstlane(csr_src[ecur]);
      nxt = *(const float4*)(xl + (size_t)s1*ODIM + 4*lane);   // prefetch next gather
    }
    float qx = lrelu(cur.x + xr4.x, 0.2f);
    float qy = lrelu(cur.y + xr4.y, 0.2f);
    float qz = lrelu(cur.z + xr4.z, 0.2f);
    float qw = lrelu(cur.w + xr4.w, 0.2f);
    float s = qx*attv.x + qy*attv.y + qz*attv.z + qw*attv.w;
    s += __shfl_xor(s, 1);
    s += __shfl_xor(s, 2);
    s += __shfl_xor(s, 4);
    // branch-free online softmax update
    float mnew = fmaxf(mrun, s);
    float wo = __expf(mrun - mnew);
    float wn = __expf(s - mnew);
    denom = denom*wo + wn;
    acc.x = fmaf(acc.x, wo, wn*cur.x);
    acc.y = fmaf(acc.y, wo, wn*cur.y);
    acc.z = fmaf(acc.z, wo, wn*cur.z);
    acc.w = fmaf(acc.w, wo, wn*cur.w);
    mrun = mnew;
  }
  float inv = 1.f/denom;
  float vx = acc.x*inv, vy = acc.y*inv, vz = acc.z*inv, vw = acc.w*inv;
  // mean over heads: sum lanes {l, l^8, l^16, ...}
  vx += __shfl_xor(vx, 8);  vx += __shfl_xor(vx, 16);  vx += __shfl_xor(vx, 32);
  vy += __shfl_xor(vy, 8);  vy += __shfl_xor(vy, 16);  vy += __shfl_xor(vy, 32);
  vz += __shfl_xor(vz, 8);  vz += __shfl_xor(vz, 16);  vz += __shfl_xor(vz, 32);
  vw += __shfl_xor(vw, 8);  vw += __shfl_xor(vw, 16);  vw += __shfl_xor(vw, 32);
  if (lane < 8){
    float4 bv = *(const float4*)(bias + 4*lane);
    float ox = vx*0.125f + bv.x;
    float oy = vy*0.125f + bv.y;
    float oz = vz*0.125f + bv.z;
    float ow = vw*0.125f + bv.w;
    if (act){
      ox = lrelu(ox, 0.01f); oy = lrelu(oy, 0.01f);
      oz = lrelu(oz, 0.01f); ow = lrelu(ow, 0.01f);
    }
    *(float4*)(out + (size_t)wid*CDIM + 4*lane) = make_float4(ox, oy, oz, ow);
  }
}

extern "C" void kernel_launch(void* const* d_in, const int* in_sizes, int n_in,
                              void* d_out, int out_size, void* d_ws, size_t ws_size,
                              hipStream_t stream){
  (void)n_in; (void)out_size; (void)ws_size;
  const float* x    = (const float*)d_in[0];
  const int*   ei   = (const int*)d_in[1];
  const float* W1l  = (const float*)d_in[2];
  const float* b1l  = (const float*)d_in[3];
  const float* W1r  = (const float*)d_in[4];
  const float* b1r  = (const float*)d_in[5];
  const float* att1 = (const float*)d_in[6];
  const float* bias1= (const float*)d_in[7];
  const float* W2l  = (const float*)d_in[8];
  const float* b2l  = (const float*)d_in[9];
  const float* W2r  = (const float*)d_in[10];
  const float* b2r  = (const float*)d_in[11];
  const float* att2 = (const float*)d_in[12];
  const float* bias2= (const float*)d_in[13];
  int n = in_sizes[0] / 64;   // 50000
  int e = in_sizes[1] / 2;    // 800000
  const int* src = ei;
  const int* dst = ei + e;

  char* ws = (char*)d_ws;
  size_t off = 0;
  auto alloc = [&](size_t bytes)->char*{
    char* p = ws + off; off += (bytes + 255) & ~(size_t)255; return p;
  };
  float* xl     = (float*)alloc((size_t)n*ODIM*4);   // 51.2 MB (reused for layer 2)
  float* xr     = (float*)alloc((size_t)n*ODIM*4);   // 51.2 MB (reused for layer 2)
  float* h      = (float*)alloc((size_t)n*CDIM*4);   // 6.4 MB layer-1 output
  int*   counts = (int*)alloc((size_t)n*4);
  int*   indptr = (int*)alloc((size_t)(n+1)*4);
  int*   cursor = (int*)alloc((size_t)n*4);
  int*   csr    = (int*)alloc((size_t)e*4);

  // CSR by dst (valid non-self edges only; self-loops handled in edge_kernel)
  zero_counts_kernel<<<(n+255)/256, 256, 0, stream>>>(counts, n);
  count_kernel<<<(e+255)/256, 256, 0, stream>>>(src, dst, counts, e);
  scan_kernel<<<1, 1024, 0, stream>>>(counts, indptr, cursor, n);
  scatter_kernel<<<(e+255)/256, 256, 0, stream>>>(src, dst, cursor, csr, e);

  // layer 1
  gemm_kernel<64><<<dim3(640,2), 256, 0, stream>>>(x, W1l, b1l, W1r, b1r, xl, xr, n);
  edge_kernel<<<(n+3)/4, 256, 0, stream>>>(xl, xr, att1, bias1, indptr, csr, h, n, 1);
  // layer 2
  gemm_kernel<32><<<dim3(640,2), 256, 0, stream>>>(h, W2l, b2l, W2r, b2r, xl, xr, n);
  edge_kernel<<<(n+3)/4, 256, 0, stream>>>(xl, xr, att2, bias2, indptr, csr, (float*)d_out, n, 0);
}